// Round 26
// baseline (112.490 us; speedup 1.0000x reference)
//
#include <hip/hip_runtime.h>
#include <hip/hip_bf16.h>
#include <math.h>
#include <stdint.h>

#define NB 4
#define NN 2048
#define NA 128
#define NK 2048                         /* table intervals; knots 0..NK */
#define RMINF 5.8f
#define RMAXF 6.0f
#define PI_OVER_DR 15.707963267948966f  /* pi / (RMAX-RMIN) */

typedef __attribute__((ext_vector_type(8))) short short8v;   // 8 bf16 (MFMA A/B frag)
typedef __attribute__((ext_vector_type(4))) float f32x4;     // MFMA C/D frag

// Exact tanh via exp: tanh(x) = 1 - 2/(e^{2x}+1). ~7 VALU inst, rel err ~1e-6.
__device__ __forceinline__ float fast_tanh(float x)
{
    x = fminf(fmaxf(x, -15.f), 15.f);
    float e = __expf(2.f * x);
    float r = __builtin_amdgcn_rcpf(e + 1.f);
    return fmaf(-2.f, r, 1.f);
}

__device__ __forceinline__ uint16_t bf16_of(float x)
{
    __hip_bfloat16 b = __float2bfloat16(x);
    return *(uint16_t*)&b;
}

__device__ __forceinline__ float bf16_to_f(uint16_t v)
{
    union { uint32_t u; float f; } c; c.u = ((uint32_t)v) << 16; return c.f;
}

// bf16-pair unpack: lo = first knot, hi = next knot.
__device__ __forceinline__ float pk_lo(uint32_t u)
{ union { uint32_t v; float f; } c; c.v = u << 16; return c.f; }
__device__ __forceinline__ float pk_hi(uint32_t u)
{ union { uint32_t v; float f; } c; c.v = u & 0xFFFF0000u; return c.f; }

// Fragment-major packed element offset for an MFMA-A/B-side matrix X[R][Ktot].
__device__ __forceinline__ size_t packed_off(int r, int k, int Ktot)
{
    return ((size_t)((r >> 4) * (Ktot >> 5) + (k >> 5)) << 9)
         + (((r & 15) + (((k >> 3) & 3) << 4)) << 3) + (k & 7);
}

// S value for table knot.
__device__ __forceinline__ float knot_S(int knot)
{
    float uu = (float)knot / (float)NK;
    return (knot == NK) ? 1e8f : uu / (1.f - uu);
}

// ---------------------------------------------------------------------------
// FUSED table prep (R25 proven): block b -> knots [8b, 8b+8), h2+G in LDS,
// packs bf16-pair rows of TBLP.
// ---------------------------------------------------------------------------
__global__ __launch_bounds__(256) void prep_table_fused(
    const float* __restrict__ We0, const float* __restrict__ be0,
    const float* __restrict__ We1, const float* __restrict__ be1,
    const float* __restrict__ We2, const float* __restrict__ be2,
    uint32_t* __restrict__ TBLP)
{
    __shared__ float h2Sh[9][50];
    __shared__ float GSh[9][100];
    const int b = blockIdx.x;
    const int t = threadIdx.x;
    const int k0 = b * 8;

    for (int idx = t; idx < 450; idx += 256) {
        int kn = idx / 50, j = idx - kn * 50;
        float S = knot_S(k0 + kn);
        float acc = be1[j];
        #pragma unroll
        for (int k = 0; k < 25; ++k) {
            float h1k = fast_tanh(fmaf(S, We0[k], be0[k]));
            acc = fmaf(h1k, We1[k * 50 + j], acc);
        }
        h2Sh[kn][j] = fast_tanh(acc);
    }
    __syncthreads();

    for (int idx = t; idx < 900; idx += 256) {
        int kn = idx / 100, j = idx - kn * 100;
        const float* h2 = h2Sh[kn];
        float acc = be2[j];
        #pragma unroll
        for (int k = 0; k < 50; ++k)
            acc = fmaf(h2[k], We2[k * 100 + j], acc);
        GSh[kn][j] = fast_tanh(acc);
    }
    __syncthreads();

    for (int idx = t; idx < 800; idx += 256) {
        int kn = idx / 100, j = idx - kn * 100;
        TBLP[(size_t)(k0 + kn) * 100 + j] =
            (uint32_t)bf16_of(GSh[kn][j]) | ((uint32_t)bf16_of(GSh[kn + 1][j]) << 16);
    }
}

// ---------------------------------------------------------------------------
// Merged weight prep: all three fitting weights in ONE launch.
// ---------------------------------------------------------------------------
__device__ __forceinline__ void wt_one(const float* W, uint16_t* Whi, uint16_t* Wlo,
                                       int K, int KP, int idx)
{
    if (idx < 256 * KP) {
        int colN = idx / KP, k = idx - colN * KP;
        float v = (colN < 240 && k < K) ? W[k * 240 + colN] : 0.f;
        uint16_t hi = bf16_of(v);
        size_t off = packed_off(colN, k, KP);
        Whi[off] = hi;
        Wlo[off] = bf16_of(v - bf16_to_f(hi));
    }
}

__global__ void prep_wt_all_kernel(
    const float* __restrict__ Wf0, const float* __restrict__ Wf1,
    const float* __restrict__ Wf2,
    uint16_t* __restrict__ W0hi, uint16_t* __restrict__ W0lo,
    uint16_t* __restrict__ W1hi, uint16_t* __restrict__ W1lo,
    uint16_t* __restrict__ W2hi, uint16_t* __restrict__ W2lo)
{
    int bid = blockIdx.x, t = threadIdx.x;
    if (bid < 1600)       wt_one(Wf0, W0hi, W0lo, 1600, 1600, bid * 256 + t);
    else if (bid < 1856)  wt_one(Wf1, W1hi, W1lo, 240, 256, (bid - 1600) * 256 + t);
    else                  wt_one(Wf2, W2hi, W2lo, 240, 256, (bid - 1856) * 256 + t);
}

// ---------------------------------------------------------------------------
// Descriptor kernel v26: TWO atoms per block (512 threads, 4096 blocks).
// Per-thread inner code identical to R24/25; bigger blocks -> steadier
// residency, half the barrier count per atom. Atom pairing preserves the
// packed-tile / XCD bijection: atom = (bid&7)*1024 + (bid>>3)*2 + la.
// ---------------------------------------------------------------------------
__global__ __launch_bounds__(512) void desc_kernel(
    const float* __restrict__ dR, const int* __restrict__ neigh,
    const uint32_t* __restrict__ TBLP,
    uint16_t* __restrict__ DRhi)
{
    const int bid = blockIdx.x;
    const int atomBase = (bid & 7) * 1024 + (bid >> 3) * 2;   // bijective pairs
    const int t = threadIdx.x;

    __shared__ float4 RiSh[2][128];
    __shared__ float2 IFSh[2][128];           // (frac, as_float(ia*100))
    __shared__ float  tmpPart[2][8][4][100];  // 25.6 KB
    __shared__ float  tmpBf[2][4][100];
    __shared__ unsigned long long balls[2][2];

    // ---- phase A: t<256 -> (la = t>>7, u = t&127) ----
    if (t < 256) {
        const int la = t >> 7;
        const int u = t & 127;
        const int atom = atomBase + la;
        const int base = atom * NA;
        float x = dR[(base + u) * 3 + 0];
        float y = dR[(base + u) * 3 + 1];
        float z = dR[(base + u) * 3 + 2];
        int nb = neigh[base + u];
        float Rij = x * x + y * y + z * z;      // squared distance (ref quirk)
        bool mask = nb > 0;
        bool mask_min = Rij < RMINF;
        float safe = (Rij > 0.f) ? Rij : 1.f;
        float s_inv = 1.f / safe;
        float s_cos = 0.5f * cosf((Rij - RMINF) * PI_OVER_DR) + 0.5f;
        float S = (mask && mask_min) ? s_inv
                : ((!mask_min && Rij < RMAXF) ? s_cos : 0.f);
        unsigned long long bal = __ballot(mask);
        if ((t & 63) == 0) balls[la][(u >> 6)] = bal;
        __syncthreads();   // #1: balls visible

        unsigned long long nb0 = ~balls[la][0], nb1 = ~balls[la][1];
        int firstBad;
        if (nb0)       firstBad = __ffsll((long long)nb0) - 1;
        else if (nb1)  firstBad = 64 + __ffsll((long long)nb1) - 1;
        else           firstBad = 128;
        float f = (u < firstBad) ? (S * s_inv) : 0.f;
        RiSh[la][u] = make_float4(S, f * x, f * y, f * z);
        float uu = S / (1.f + S);               // match prep map exactly
        float pos = fminf(uu * (float)NK, (float)NK - 0.001f);
        float fi = floorf(pos);
        IFSh[la][u] = make_float2(pos - fi, __int_as_float((int)fi * 100));
    } else {
        __syncthreads();   // #1 (inactive threads must still arrive)
    }
    __syncthreads();   // #2: RiSh + IFSh ready for both atoms

    // ---- phase B: aqa = t>>5 in [0,16): la = aqa>>3, aq = aqa&7; jq<25 ----
    {
        const int aqa = t >> 5;
        const int la = aqa >> 3;
        const int aq = aqa & 7;
        const int jq = t & 31;
        if (jq < 25) {
            const uint32_t* TPq = TBLP + jq * 4;
            const int a0 = aq * 16;
            float acc00 = 0.f, acc01 = 0.f, acc02 = 0.f, acc03 = 0.f;
            float acc10 = 0.f, acc11 = 0.f, acc12 = 0.f, acc13 = 0.f;
            float acc20 = 0.f, acc21 = 0.f, acc22 = 0.f, acc23 = 0.f;
            float acc30 = 0.f, acc31 = 0.f, acc32 = 0.f, acc33 = 0.f;

            float2 ifv = IFSh[la][a0];
            float  cf  = ifv.x;
            int    ia  = __float_as_int(ifv.y);
            uint4  pk  = *(const uint4*)(TPq + ia);
            #pragma unroll
            for (int i = 0; i < 16; ++i) {
                float t0x = pk_lo(pk.x), t1x = pk_hi(pk.x);
                float t0y = pk_lo(pk.y), t1y = pk_hi(pk.y);
                float t0z = pk_lo(pk.z), t1z = pk_hi(pk.z);
                float t0w = pk_lo(pk.w), t1w = pk_hi(pk.w);
                float g0 = fmaf(cf, t1x - t0x, t0x);
                float g1 = fmaf(cf, t1y - t0y, t0y);
                float g2 = fmaf(cf, t1z - t0z, t0z);
                float g3 = fmaf(cf, t1w - t0w, t0w);
                if (i + 1 < 16) {
                    float2 nx = IFSh[la][a0 + i + 1];
                    cf = nx.x;
                    int ian = __float_as_int(nx.y);
                    pk = *(const uint4*)(TPq + ian);
                }
                float4 cri = RiSh[la][a0 + i];
                acc00 = fmaf(cri.x, g0, acc00); acc01 = fmaf(cri.x, g1, acc01);
                acc02 = fmaf(cri.x, g2, acc02); acc03 = fmaf(cri.x, g3, acc03);
                acc10 = fmaf(cri.y, g0, acc10); acc11 = fmaf(cri.y, g1, acc11);
                acc12 = fmaf(cri.y, g2, acc12); acc13 = fmaf(cri.y, g3, acc13);
                acc20 = fmaf(cri.z, g0, acc20); acc21 = fmaf(cri.z, g1, acc21);
                acc22 = fmaf(cri.z, g2, acc22); acc23 = fmaf(cri.z, g3, acc23);
                acc30 = fmaf(cri.w, g0, acc30); acc31 = fmaf(cri.w, g1, acc31);
                acc32 = fmaf(cri.w, g2, acc32); acc33 = fmaf(cri.w, g3, acc33);
            }
            *(float4*)&tmpPart[la][aq][0][jq * 4] = make_float4(acc00, acc01, acc02, acc03);
            *(float4*)&tmpPart[la][aq][1][jq * 4] = make_float4(acc10, acc11, acc12, acc13);
            *(float4*)&tmpPart[la][aq][2][jq * 4] = make_float4(acc20, acc21, acc22, acc23);
            *(float4*)&tmpPart[la][aq][3][jq * 4] = make_float4(acc30, acc31, acc32, acc33);
        }
    }
    __syncthreads();   // #3

    // ---- reduce 8 a-chunks, both atoms (800 items over 512 threads) ----
    for (int idx = t; idx < 800; idx += 512) {
        int la = idx / 400;
        int rem = idx - la * 400;
        int c = rem / 100, j = rem - c * 100;
        float s = tmpPart[la][0][c][j] + tmpPart[la][1][c][j]
                + tmpPart[la][2][c][j] + tmpPart[la][3][c][j]
                + tmpPart[la][4][c][j] + tmpPart[la][5][c][j]
                + tmpPart[la][6][c][j] + tmpPart[la][7][c][j];
        tmpBf[la][c][j] = s;
    }
    __syncthreads();   // #4

    // ---- phase C: la = t>>8, half = (t>>7)&1, u = t&127 ----
    {
        const int la = t >> 8;
        const int half = (t >> 7) & 1;
        const int u = t & 127;
        if (u < 100) {
            const int atom = atomBase + la;
            float b0 = tmpBf[la][0][u];
            float b1 = tmpBf[la][1][u];
            float b2 = tmpBf[la][2][u];
            float b3 = tmpBf[la][3][u];
            const int i0 = half * 8;
            #pragma unroll
            for (int ii = 0; ii < 8; ++ii) {
                int i = i0 + ii;
                float v = tmpBf[la][0][i] * b0 + tmpBf[la][1][i] * b1
                        + tmpBf[la][2][i] * b2 + tmpBf[la][3][i] * b3;
                DRhi[packed_off(atom, i * 100 + u, 1600)] = bf16_of(v);
            }
        }
    }
}

// ---------------------------------------------------------------------------
// gemm1 fused: 2-term (A single plane) K=1600 full-K with bias+tanh epilogue
// writing bf16 hi/lo PACKED. Grid (128,4), 64x64 per block = whole packed tiles.
// ---------------------------------------------------------------------------
template<int KP>
__global__ __launch_bounds__(256, 4) void gemm1_fused(
    const uint16_t* __restrict__ Ahi,
    const uint16_t* __restrict__ Wthi, const uint16_t* __restrict__ Wtlo,
    const float* __restrict__ bias,
    uint16_t* __restrict__ Ohi, uint16_t* __restrict__ Olo)
{
    constexpr int KT = KP >> 5;
    const int tid = threadIdx.x;
    const int wid = tid >> 6, lane = tid & 63;
    const int mg = wid >> 1, ng = wid & 1;
    const int mt0 = blockIdx.x * 4 + mg * 2;
    const int nt0 = blockIdx.y * 4 + ng * 2;

    const size_t aB0 = ((size_t)(mt0 + 0) * KT) * 512 + lane * 8;
    const size_t aB1 = ((size_t)(mt0 + 1) * KT) * 512 + lane * 8;
    const size_t bB0 = ((size_t)(nt0 + 0) * KT) * 512 + lane * 8;
    const size_t bB1 = ((size_t)(nt0 + 1) * KT) * 512 + lane * 8;

    f32x4 acc[2][2];
    #pragma unroll
    for (int m = 0; m < 2; ++m)
        #pragma unroll
        for (int n = 0; n < 2; ++n) acc[m][n] = (f32x4){0.f, 0.f, 0.f, 0.f};

    short8v f[2][6];

#define LOADSET(B, S) do {                                       \
        f[B][0] = *(const short8v*)(Ahi  + aB0 + (S) * 512);     \
        f[B][1] = *(const short8v*)(Ahi  + aB1 + (S) * 512);     \
        f[B][2] = *(const short8v*)(Wthi + bB0 + (S) * 512);     \
        f[B][3] = *(const short8v*)(Wthi + bB1 + (S) * 512);     \
        f[B][4] = *(const short8v*)(Wtlo + bB0 + (S) * 512);     \
        f[B][5] = *(const short8v*)(Wtlo + bB1 + (S) * 512);     \
    } while (0)

    LOADSET(0, 0);
    #pragma unroll
    for (int s = 0; s < KT; ++s) {
        const int b = s & 1;
        if (s + 1 < KT) LOADSET(b ^ 1, s + 1);
        #pragma unroll
        for (int m = 0; m < 2; ++m)
            #pragma unroll
            for (int n = 0; n < 2; ++n) {
                acc[m][n] = __builtin_amdgcn_mfma_f32_16x16x32_bf16(f[b][m], f[b][2 + n], acc[m][n], 0, 0, 0);
                acc[m][n] = __builtin_amdgcn_mfma_f32_16x16x32_bf16(f[b][m], f[b][4 + n], acc[m][n], 0, 0, 0);
            }
    }
#undef LOADSET

    const int ar = lane & 15, kg = lane >> 4;
    #pragma unroll
    for (int n = 0; n < 2; ++n) {
        int col = (nt0 + n) * 16 + ar;
        bool valid = col < 240;
        float bv = valid ? bias[col] : 0.f;
        #pragma unroll
        for (int m = 0; m < 2; ++m) {
            #pragma unroll
            for (int r = 0; r < 4; ++r) {
                int row = (mt0 + m) * 16 + kg * 4 + r;
                float v = valid ? fast_tanh(acc[m][n][r] + bv) : 0.f;
                uint16_t hi = bf16_of(v);
                size_t off = packed_off(row, col, 256);
                Ohi[off] = hi;
                Olo[off] = bf16_of(v - bf16_to_f(hi));
            }
        }
    }
}

// ---------------------------------------------------------------------------
// Fused small GEMM (K=256, A split hi/lo, 3-term) with bias+tanh epilogue,
// writing bf16 hi/lo PACKED directly (middle fitting layer).
// ---------------------------------------------------------------------------
template<int KP>
__global__ __launch_bounds__(256, 4) void gemm_fused(
    const uint16_t* __restrict__ Ahi, const uint16_t* __restrict__ Alo,
    const uint16_t* __restrict__ Wthi, const uint16_t* __restrict__ Wtlo,
    const float* __restrict__ bias,
    uint16_t* __restrict__ Ohi, uint16_t* __restrict__ Olo)
{
    constexpr int KT = KP >> 5;
    const int tid = threadIdx.x;
    const int wid = tid >> 6, lane = tid & 63;
    const int mg = wid >> 1, ng = wid & 1;
    const int mt0 = blockIdx.x * 4 + mg * 2;
    const int nt0 = blockIdx.y * 4 + ng * 2;

    const size_t aB0 = ((size_t)(mt0 + 0) * KT) * 512 + lane * 8;
    const size_t aB1 = ((size_t)(mt0 + 1) * KT) * 512 + lane * 8;
    const size_t bB0 = ((size_t)(nt0 + 0) * KT) * 512 + lane * 8;
    const size_t bB1 = ((size_t)(nt0 + 1) * KT) * 512 + lane * 8;

    f32x4 acc[2][2];
    #pragma unroll
    for (int m = 0; m < 2; ++m)
        #pragma unroll
        for (int n = 0; n < 2; ++n) acc[m][n] = (f32x4){0.f, 0.f, 0.f, 0.f};

    short8v f[2][8];

#define LOADSET(B, S) do {                                       \
        f[B][0] = *(const short8v*)(Ahi  + aB0 + (S) * 512);     \
        f[B][1] = *(const short8v*)(Ahi  + aB1 + (S) * 512);     \
        f[B][2] = *(const short8v*)(Alo  + aB0 + (S) * 512);     \
        f[B][3] = *(const short8v*)(Alo  + aB1 + (S) * 512);     \
        f[B][4] = *(const short8v*)(Wthi + bB0 + (S) * 512);     \
        f[B][5] = *(const short8v*)(Wthi + bB1 + (S) * 512);     \
        f[B][6] = *(const short8v*)(Wtlo + bB0 + (S) * 512);     \
        f[B][7] = *(const short8v*)(Wtlo + bB1 + (S) * 512);     \
    } while (0)

    LOADSET(0, 0);
    #pragma unroll
    for (int s = 0; s < KT; ++s) {
        const int b = s & 1;
        if (s + 1 < KT) LOADSET(b ^ 1, s + 1);
        #pragma unroll
        for (int m = 0; m < 2; ++m)
            #pragma unroll
            for (int n = 0; n < 2; ++n) {
                acc[m][n] = __builtin_amdgcn_mfma_f32_16x16x32_bf16(f[b][m],     f[b][4 + n], acc[m][n], 0, 0, 0);
                acc[m][n] = __builtin_amdgcn_mfma_f32_16x16x32_bf16(f[b][m],     f[b][6 + n], acc[m][n], 0, 0, 0);
                acc[m][n] = __builtin_amdgcn_mfma_f32_16x16x32_bf16(f[b][2 + m], f[b][4 + n], acc[m][n], 0, 0, 0);
            }
    }
#undef LOADSET

    const int ar = lane & 15, kg = lane >> 4;
    #pragma unroll
    for (int n = 0; n < 2; ++n) {
        int col = (nt0 + n) * 16 + ar;
        bool valid = col < 240;
        float bv = valid ? bias[col] : 0.f;
        #pragma unroll
        for (int m = 0; m < 2; ++m) {
            #pragma unroll
            for (int r = 0; r < 4; ++r) {
                int row = (mt0 + m) * 16 + kg * 4 + r;
                float v = valid ? fast_tanh(acc[m][n][r] + bv) : 0.f;
                uint16_t hi = bf16_of(v);
                size_t off = packed_off(row, col, 256);
                Ohi[off] = hi;
                Olo[off] = bf16_of(v - bf16_to_f(hi));
            }
        }
    }
}

// ---------------------------------------------------------------------------
// Last fitting GEMM (K=256, 3-term) + fused Wf3 dot: h3 never materialized.
// Each WAVE owns a disjoint 32-col slice: partial index = by*2 + ng (8 total).
// ---------------------------------------------------------------------------
template<int KP>
__global__ __launch_bounds__(256, 4) void gemm_fused_dot(
    const uint16_t* __restrict__ Ahi, const uint16_t* __restrict__ Alo,
    const uint16_t* __restrict__ Wthi, const uint16_t* __restrict__ Wtlo,
    const float* __restrict__ bias, const float* __restrict__ Wf3,
    float* __restrict__ EiPart)
{
    constexpr int KT = KP >> 5;
    const int tid = threadIdx.x;
    const int wid = tid >> 6, lane = tid & 63;
    const int mg = wid >> 1, ng = wid & 1;
    const int mt0 = blockIdx.x * 4 + mg * 2;
    const int nt0 = blockIdx.y * 4 + ng * 2;

    const size_t aB0 = ((size_t)(mt0 + 0) * KT) * 512 + lane * 8;
    const size_t aB1 = ((size_t)(mt0 + 1) * KT) * 512 + lane * 8;
    const size_t bB0 = ((size_t)(nt0 + 0) * KT) * 512 + lane * 8;
    const size_t bB1 = ((size_t)(nt0 + 1) * KT) * 512 + lane * 8;

    f32x4 acc[2][2];
    #pragma unroll
    for (int m = 0; m < 2; ++m)
        #pragma unroll
        for (int n = 0; n < 2; ++n) acc[m][n] = (f32x4){0.f, 0.f, 0.f, 0.f};

    short8v f[2][8];

#define LOADSET(B, S) do {                                       \
        f[B][0] = *(const short8v*)(Ahi  + aB0 + (S) * 512);     \
        f[B][1] = *(const short8v*)(Ahi  + aB1 + (S) * 512);     \
        f[B][2] = *(const short8v*)(Alo  + aB0 + (S) * 512);     \
        f[B][3] = *(const short8v*)(Alo  + aB1 + (S) * 512);     \
        f[B][4] = *(const short8v*)(Wthi + bB0 + (S) * 512);     \
        f[B][5] = *(const short8v*)(Wthi + bB1 + (S) * 512);     \
        f[B][6] = *(const short8v*)(Wtlo + bB0 + (S) * 512);     \
        f[B][7] = *(const short8v*)(Wtlo + bB1 + (S) * 512);     \
    } while (0)

    LOADSET(0, 0);
    #pragma unroll
    for (int s = 0; s < KT; ++s) {
        const int b = s & 1;
        if (s + 1 < KT) LOADSET(b ^ 1, s + 1);
        #pragma unroll
        for (int m = 0; m < 2; ++m)
            #pragma unroll
            for (int n = 0; n < 2; ++n) {
                acc[m][n] = __builtin_amdgcn_mfma_f32_16x16x32_bf16(f[b][m],     f[b][4 + n], acc[m][n], 0, 0, 0);
                acc[m][n] = __builtin_amdgcn_mfma_f32_16x16x32_bf16(f[b][m],     f[b][6 + n], acc[m][n], 0, 0, 0);
                acc[m][n] = __builtin_amdgcn_mfma_f32_16x16x32_bf16(f[b][2 + m], f[b][4 + n], acc[m][n], 0, 0, 0);
            }
    }
#undef LOADSET

    const int ar = lane & 15, kg = lane >> 4;
    float p[2][4];
    #pragma unroll
    for (int m = 0; m < 2; ++m)
        #pragma unroll
        for (int r = 0; r < 4; ++r) p[m][r] = 0.f;

    #pragma unroll
    for (int n = 0; n < 2; ++n) {
        int col = (nt0 + n) * 16 + ar;
        bool valid = col < 240;
        float bv = valid ? bias[col] : 0.f;
        float w3 = valid ? Wf3[col] : 0.f;
        #pragma unroll
        for (int m = 0; m < 2; ++m) {
            #pragma unroll
            for (int r = 0; r < 4; ++r) {
                float v = valid ? fast_tanh(acc[m][n][r] + bv) : 0.f;
                p[m][r] = fmaf(v, w3, p[m][r]);
            }
        }
    }
    #pragma unroll
    for (int m = 0; m < 2; ++m)
        #pragma unroll
        for (int r = 0; r < 4; ++r) {
            p[m][r] += __shfl_xor(p[m][r], 1, 64);
            p[m][r] += __shfl_xor(p[m][r], 2, 64);
            p[m][r] += __shfl_xor(p[m][r], 4, 64);
            p[m][r] += __shfl_xor(p[m][r], 8, 64);
        }
    if (ar == 0) {
        const int slice = blockIdx.y * 2 + ng;   // 8 disjoint col-slices
        #pragma unroll
        for (int m = 0; m < 2; ++m)
            #pragma unroll
            for (int r = 0; r < 4; ++r) {
                int row = (mt0 + m) * 16 + kg * 4 + r;
                EiPart[(size_t)slice * 8192 + row] = p[m][r];
            }
    }
}

// ---------------------------------------------------------------------------
// Ei = sum over 8 slices of EiPart + bf3; Etot[b] = sum Ei. One block per b.
// ---------------------------------------------------------------------------
__global__ __launch_bounds__(256) void ei_etot_kernel(
    const float* __restrict__ EiPart, const float* __restrict__ bf3,
    float* __restrict__ out)
{
    __shared__ float red[256];
    int b = blockIdx.x, t = threadIdx.x;
    float b3 = bf3[0];
    float s = 0.f;
    for (int i = t; i < NN; i += 256) {
        int atom = b * NN + i;
        float e = b3;
        #pragma unroll
        for (int z = 0; z < 8; ++z) e += EiPart[(size_t)z * 8192 + atom];
        out[4 + atom] = e;
        s += e;
    }
    red[t] = s;
    __syncthreads();
    for (int w = 128; w; w >>= 1) {
        if (t < w) red[t] += red[t + w];
        __syncthreads();
    }
    if (t == 0) out[b] = red[0];
}

// ---------------------------------------------------------------------------
extern "C" void kernel_launch(void* const* d_in, const int* in_sizes, int n_in,
                              void* d_out, int out_size, void* d_ws, size_t ws_size,
                              hipStream_t stream)
{
    const float* dR    = (const float*)d_in[0];
    const int*   neigh = (const int*)d_in[1];
    const float* We0   = (const float*)d_in[2];
    const float* be0   = (const float*)d_in[3];
    const float* We1   = (const float*)d_in[4];
    const float* be1   = (const float*)d_in[5];
    const float* We2   = (const float*)d_in[6];
    const float* be2   = (const float*)d_in[7];
    const float* Wf0   = (const float*)d_in[8];
    const float* bf0   = (const float*)d_in[9];
    const float* Wf1   = (const float*)d_in[10];
    const float* bf1   = (const float*)d_in[11];
    const float* Wf2   = (const float*)d_in[12];
    const float* bf2   = (const float*)d_in[13];
    const float* Wf3   = (const float*)d_in[14];
    const float* bf3   = (const float*)d_in[15];
    float* out = (float*)d_out;

    char* ws = (char*)d_ws;
    uint16_t* Wt0hi  = (uint16_t*)(ws + 32768);               // 819200
    uint16_t* Wt0lo  = (uint16_t*)(ws + 851968);              // 819200
    uint16_t* Wt1hi  = (uint16_t*)(ws + 1671168);             // 131072
    uint16_t* Wt1lo  = (uint16_t*)(ws + 1802240);             // 131072
    uint16_t* Wt2hi  = (uint16_t*)(ws + 1933312);             // 131072
    uint16_t* Wt2lo  = (uint16_t*)(ws + 2064384);             // 131072
    uint16_t* DRhi   = (uint16_t*)(ws + 2195456);             // 26214400
    uint16_t* hAhi   = (uint16_t*)(ws + 54624256);            // 4194304
    uint16_t* hAlo   = (uint16_t*)(ws + 58818560);            // 4194304
    uint16_t* hBhi   = (uint16_t*)(ws + 63012864);            // 4194304
    uint16_t* hBlo   = (uint16_t*)(ws + 67207168);            // 4194304
    float*    EiPart = (float*)(ws + 71401472);               // 262144 (8 slices)
    // TBLP bf16-pair table (819200) aliases hBhi: written by prep_table_fused,
    // read only by desc, dead before gemm_fused writes hB.
    uint32_t* TBLP = (uint32_t*)(ws + 63012864);

    prep_table_fused<<<256, 256, 0, stream>>>(We0, be0, We1, be1, We2, be2, TBLP);
    prep_wt_all_kernel<<<2112, 256, 0, stream>>>(Wf0, Wf1, Wf2,
                                                 Wt0hi, Wt0lo, Wt1hi, Wt1lo,
                                                 Wt2hi, Wt2lo);

    desc_kernel<<<NB * NN / 2, 512, 0, stream>>>(dR, neigh, TBLP, DRhi);

    gemm1_fused<1600><<<dim3(128, 4), 256, 0, stream>>>(DRhi, Wt0hi, Wt0lo, bf0, hAhi, hAlo);
    gemm_fused<256><<<dim3(128, 4), 256, 0, stream>>>(hAhi, hAlo, Wt1hi, Wt1lo, bf1, hBhi, hBlo);
    gemm_fused_dot<256><<<dim3(128, 4), 256, 0, stream>>>(hBhi, hBlo, Wt2hi, Wt2lo, bf2, Wf3, EiPart);

    ei_etot_kernel<<<NB, 256, 0, stream>>>(EiPart, bf3, out);
}

// Round 27
// 108.409 us; speedup vs baseline: 1.0376x; 1.0376x over previous
//
#include <hip/hip_runtime.h>
#include <hip/hip_bf16.h>
#include <math.h>
#include <stdint.h>

#define NB 4
#define NN 2048
#define NA 128
#define NK 2048                         /* table intervals; knots 0..NK */
#define RMINF 5.8f
#define RMAXF 6.0f
#define PI_OVER_DR 15.707963267948966f  /* pi / (RMAX-RMIN) */

typedef __attribute__((ext_vector_type(8))) short short8v;   // 8 bf16 (MFMA A/B frag)
typedef __attribute__((ext_vector_type(4))) float f32x4;     // MFMA C/D frag

// Exact tanh via exp: tanh(x) = 1 - 2/(e^{2x}+1). ~7 VALU inst, rel err ~1e-6.
__device__ __forceinline__ float fast_tanh(float x)
{
    x = fminf(fmaxf(x, -15.f), 15.f);
    float e = __expf(2.f * x);
    float r = __builtin_amdgcn_rcpf(e + 1.f);
    return fmaf(-2.f, r, 1.f);
}

__device__ __forceinline__ uint16_t bf16_of(float x)
{
    __hip_bfloat16 b = __float2bfloat16(x);
    return *(uint16_t*)&b;
}

__device__ __forceinline__ float bf16_to_f(uint16_t v)
{
    union { uint32_t u; float f; } c; c.u = ((uint32_t)v) << 16; return c.f;
}

// bf16-pair unpack: lo = first knot, hi = next knot.
__device__ __forceinline__ float pk_lo(uint32_t u)
{ union { uint32_t v; float f; } c; c.v = u << 16; return c.f; }
__device__ __forceinline__ float pk_hi(uint32_t u)
{ union { uint32_t v; float f; } c; c.v = u & 0xFFFF0000u; return c.f; }

// Fragment-major packed element offset for an MFMA-A/B-side matrix X[R][Ktot].
__device__ __forceinline__ size_t packed_off(int r, int k, int Ktot)
{
    return ((size_t)((r >> 4) * (Ktot >> 5) + (k >> 5)) << 9)
         + (((r & 15) + (((k >> 3) & 3) << 4)) << 3) + (k & 7);
}

// S value for table knot.
__device__ __forceinline__ float knot_S(int knot)
{
    float uu = (float)knot / (float)NK;
    return (knot == NK) ? 1e8f : uu / (1.f - uu);
}

// ---------------------------------------------------------------------------
// FUSED table prep: block b -> knots [8b, 8b+8), h2+G in LDS, packs bf16-pair
// rows of TBLP. H2/Gfull never hit global memory.
// ---------------------------------------------------------------------------
__global__ __launch_bounds__(256) void prep_table_fused(
    const float* __restrict__ We0, const float* __restrict__ be0,
    const float* __restrict__ We1, const float* __restrict__ be1,
    const float* __restrict__ We2, const float* __restrict__ be2,
    uint32_t* __restrict__ TBLP)
{
    __shared__ float h2Sh[9][50];
    __shared__ float GSh[9][100];
    const int b = blockIdx.x;
    const int t = threadIdx.x;
    const int k0 = b * 8;

    for (int idx = t; idx < 450; idx += 256) {
        int kn = idx / 50, j = idx - kn * 50;
        float S = knot_S(k0 + kn);
        float acc = be1[j];
        #pragma unroll
        for (int k = 0; k < 25; ++k) {
            float h1k = fast_tanh(fmaf(S, We0[k], be0[k]));
            acc = fmaf(h1k, We1[k * 50 + j], acc);
        }
        h2Sh[kn][j] = fast_tanh(acc);
    }
    __syncthreads();

    for (int idx = t; idx < 900; idx += 256) {
        int kn = idx / 100, j = idx - kn * 100;
        const float* h2 = h2Sh[kn];
        float acc = be2[j];
        #pragma unroll
        for (int k = 0; k < 50; ++k)
            acc = fmaf(h2[k], We2[k * 100 + j], acc);
        GSh[kn][j] = fast_tanh(acc);
    }
    __syncthreads();

    for (int idx = t; idx < 800; idx += 256) {
        int kn = idx / 100, j = idx - kn * 100;
        TBLP[(size_t)(k0 + kn) * 100 + j] =
            (uint32_t)bf16_of(GSh[kn][j]) | ((uint32_t)bf16_of(GSh[kn + 1][j]) << 16);
    }
}

// ---------------------------------------------------------------------------
// Merged weight prep: all three fitting weights in ONE launch.
// ---------------------------------------------------------------------------
__device__ __forceinline__ void wt_one(const float* W, uint16_t* Whi, uint16_t* Wlo,
                                       int K, int KP, int idx)
{
    if (idx < 256 * KP) {
        int colN = idx / KP, k = idx - colN * KP;
        float v = (colN < 240 && k < K) ? W[k * 240 + colN] : 0.f;
        uint16_t hi = bf16_of(v);
        size_t off = packed_off(colN, k, KP);
        Whi[off] = hi;
        Wlo[off] = bf16_of(v - bf16_to_f(hi));
    }
}

__global__ void prep_wt_all_kernel(
    const float* __restrict__ Wf0, const float* __restrict__ Wf1,
    const float* __restrict__ Wf2,
    uint16_t* __restrict__ W0hi, uint16_t* __restrict__ W0lo,
    uint16_t* __restrict__ W1hi, uint16_t* __restrict__ W1lo,
    uint16_t* __restrict__ W2hi, uint16_t* __restrict__ W2lo)
{
    int bid = blockIdx.x, t = threadIdx.x;
    if (bid < 1600)       wt_one(Wf0, W0hi, W0lo, 1600, 1600, bid * 256 + t);
    else if (bid < 1856)  wt_one(Wf1, W1hi, W1lo, 240, 256, (bid - 1600) * 256 + t);
    else                  wt_one(Wf2, W2hi, W2lo, 240, 256, (bid - 1856) * 256 + t);
}

// ---------------------------------------------------------------------------
// Descriptor kernel (R24/25 best): j-quad gather from bf16-PAIR table, one
// uint4 load per iteration. DR single bf16 plane PACKED, atom-swizzled.
// ---------------------------------------------------------------------------
__global__ __launch_bounds__(256) void desc_kernel(
    const float* __restrict__ dR, const int* __restrict__ neigh,
    const uint32_t* __restrict__ TBLP,
    uint16_t* __restrict__ DRhi)
{
    const int bid = blockIdx.x;
    const int atom = (bid & 7) * 1024 + (bid >> 3);   // bijection on [0,8192)
    const int t = threadIdx.x;

    __shared__ float4 RiSh[128];
    __shared__ float2 IFSh[128];            // (frac, as_float(ia*100))
    __shared__ float  tmpPart[8][4][100];   // 12.8 KB
    __shared__ float  tmpBf[4][100];
    __shared__ unsigned long long balls[2];

    float x = 0.f, y = 0.f, z = 0.f, S = 0.f, s_inv = 1.f;
    if (t < 128) {
        const int base = atom * NA;
        x = dR[(base + t) * 3 + 0];
        y = dR[(base + t) * 3 + 1];
        z = dR[(base + t) * 3 + 2];
        int nb = neigh[base + t];
        float Rij = x * x + y * y + z * z;      // squared distance (ref quirk)
        bool mask = nb > 0;
        bool mask_min = Rij < RMINF;
        float safe = (Rij > 0.f) ? Rij : 1.f;
        s_inv = 1.f / safe;
        float s_cos = 0.5f * cosf((Rij - RMINF) * PI_OVER_DR) + 0.5f;
        S = (mask && mask_min) ? s_inv
          : ((!mask_min && Rij < RMAXF) ? s_cos : 0.f);
        unsigned long long bal = __ballot(mask);
        if ((t & 63) == 0) balls[t >> 6] = bal;
    }
    __syncthreads();   // #1

    if (t < 128) {
        unsigned long long nb0 = ~balls[0], nb1 = ~balls[1];
        int firstBad;
        if (nb0)       firstBad = __ffsll((long long)nb0) - 1;
        else if (nb1)  firstBad = 64 + __ffsll((long long)nb1) - 1;
        else           firstBad = 128;
        float f = (t < firstBad) ? (S * s_inv) : 0.f;
        RiSh[t] = make_float4(S, f * x, f * y, f * z);
        float uu = S / (1.f + S);               // match prep map exactly
        float pos = fminf(uu * (float)NK, (float)NK - 0.001f);
        float fi = floorf(pos);
        IFSh[t] = make_float2(pos - fi, __int_as_float((int)fi * 100));
    }
    __syncthreads();   // #2

    const int aq = t >> 5;
    const int jq = t & 31;
    if (jq < 25) {
        const uint32_t* TPq = TBLP + jq * 4;
        const int a0 = aq * 16;
        float acc00 = 0.f, acc01 = 0.f, acc02 = 0.f, acc03 = 0.f;
        float acc10 = 0.f, acc11 = 0.f, acc12 = 0.f, acc13 = 0.f;
        float acc20 = 0.f, acc21 = 0.f, acc22 = 0.f, acc23 = 0.f;
        float acc30 = 0.f, acc31 = 0.f, acc32 = 0.f, acc33 = 0.f;

        float2 ifv = IFSh[a0];
        float  cf  = ifv.x;
        int    ia  = __float_as_int(ifv.y);
        uint4  pk  = *(const uint4*)(TPq + ia);
        #pragma unroll
        for (int i = 0; i < 16; ++i) {
            float t0x = pk_lo(pk.x), t1x = pk_hi(pk.x);
            float t0y = pk_lo(pk.y), t1y = pk_hi(pk.y);
            float t0z = pk_lo(pk.z), t1z = pk_hi(pk.z);
            float t0w = pk_lo(pk.w), t1w = pk_hi(pk.w);
            float g0 = fmaf(cf, t1x - t0x, t0x);
            float g1 = fmaf(cf, t1y - t0y, t0y);
            float g2 = fmaf(cf, t1z - t0z, t0z);
            float g3 = fmaf(cf, t1w - t0w, t0w);
            if (i + 1 < 16) {
                float2 nx = IFSh[a0 + i + 1];
                cf = nx.x;
                int ian = __float_as_int(nx.y);
                pk = *(const uint4*)(TPq + ian);
            }
            float4 cri = RiSh[a0 + i];
            acc00 = fmaf(cri.x, g0, acc00); acc01 = fmaf(cri.x, g1, acc01);
            acc02 = fmaf(cri.x, g2, acc02); acc03 = fmaf(cri.x, g3, acc03);
            acc10 = fmaf(cri.y, g0, acc10); acc11 = fmaf(cri.y, g1, acc11);
            acc12 = fmaf(cri.y, g2, acc12); acc13 = fmaf(cri.y, g3, acc13);
            acc20 = fmaf(cri.z, g0, acc20); acc21 = fmaf(cri.z, g1, acc21);
            acc22 = fmaf(cri.z, g2, acc22); acc23 = fmaf(cri.z, g3, acc23);
            acc30 = fmaf(cri.w, g0, acc30); acc31 = fmaf(cri.w, g1, acc31);
            acc32 = fmaf(cri.w, g2, acc32); acc33 = fmaf(cri.w, g3, acc33);
        }
        *(float4*)&tmpPart[aq][0][jq * 4] = make_float4(acc00, acc01, acc02, acc03);
        *(float4*)&tmpPart[aq][1][jq * 4] = make_float4(acc10, acc11, acc12, acc13);
        *(float4*)&tmpPart[aq][2][jq * 4] = make_float4(acc20, acc21, acc22, acc23);
        *(float4*)&tmpPart[aq][3][jq * 4] = make_float4(acc30, acc31, acc32, acc33);
    }
    __syncthreads();   // #3

    for (int idx = t; idx < 400; idx += 256) {
        int c = idx / 100, j = idx - c * 100;
        float s = tmpPart[0][c][j] + tmpPart[1][c][j]
                + tmpPart[2][c][j] + tmpPart[3][c][j]
                + tmpPart[4][c][j] + tmpPart[5][c][j]
                + tmpPart[6][c][j] + tmpPart[7][c][j];
        tmpBf[c][j] = s;
    }
    __syncthreads();   // #4

    const int half = t >> 7;
    const int u = t & 127;
    if (u < 100) {
        float b0 = tmpBf[0][u];
        float b1 = tmpBf[1][u];
        float b2 = tmpBf[2][u];
        float b3 = tmpBf[3][u];
        const int i0 = half * 8;
        #pragma unroll
        for (int ii = 0; ii < 8; ++ii) {
            int i = i0 + ii;
            float v = tmpBf[0][i] * b0 + tmpBf[1][i] * b1
                    + tmpBf[2][i] * b2 + tmpBf[3][i] * b3;
            DRhi[packed_off(atom, i * 100 + u, 1600)] = bf16_of(v);
        }
    }
}

// ---------------------------------------------------------------------------
// gemm1 fused: 2-term (A single plane) K=1600 full-K with bias+tanh epilogue
// writing bf16 hi/lo PACKED. Grid (128,4), 64x64 per block = whole packed tiles.
// ---------------------------------------------------------------------------
template<int KP>
__global__ __launch_bounds__(256, 4) void gemm1_fused(
    const uint16_t* __restrict__ Ahi,
    const uint16_t* __restrict__ Wthi, const uint16_t* __restrict__ Wtlo,
    const float* __restrict__ bias,
    uint16_t* __restrict__ Ohi, uint16_t* __restrict__ Olo)
{
    constexpr int KT = KP >> 5;
    const int tid = threadIdx.x;
    const int wid = tid >> 6, lane = tid & 63;
    const int mg = wid >> 1, ng = wid & 1;
    const int mt0 = blockIdx.x * 4 + mg * 2;
    const int nt0 = blockIdx.y * 4 + ng * 2;

    const size_t aB0 = ((size_t)(mt0 + 0) * KT) * 512 + lane * 8;
    const size_t aB1 = ((size_t)(mt0 + 1) * KT) * 512 + lane * 8;
    const size_t bB0 = ((size_t)(nt0 + 0) * KT) * 512 + lane * 8;
    const size_t bB1 = ((size_t)(nt0 + 1) * KT) * 512 + lane * 8;

    f32x4 acc[2][2];
    #pragma unroll
    for (int m = 0; m < 2; ++m)
        #pragma unroll
        for (int n = 0; n < 2; ++n) acc[m][n] = (f32x4){0.f, 0.f, 0.f, 0.f};

    short8v f[2][6];

#define LOADSET(B, S) do {                                       \
        f[B][0] = *(const short8v*)(Ahi  + aB0 + (S) * 512);     \
        f[B][1] = *(const short8v*)(Ahi  + aB1 + (S) * 512);     \
        f[B][2] = *(const short8v*)(Wthi + bB0 + (S) * 512);     \
        f[B][3] = *(const short8v*)(Wthi + bB1 + (S) * 512);     \
        f[B][4] = *(const short8v*)(Wtlo + bB0 + (S) * 512);     \
        f[B][5] = *(const short8v*)(Wtlo + bB1 + (S) * 512);     \
    } while (0)

    LOADSET(0, 0);
    #pragma unroll
    for (int s = 0; s < KT; ++s) {
        const int b = s & 1;
        if (s + 1 < KT) LOADSET(b ^ 1, s + 1);
        #pragma unroll
        for (int m = 0; m < 2; ++m)
            #pragma unroll
            for (int n = 0; n < 2; ++n) {
                acc[m][n] = __builtin_amdgcn_mfma_f32_16x16x32_bf16(f[b][m], f[b][2 + n], acc[m][n], 0, 0, 0);
                acc[m][n] = __builtin_amdgcn_mfma_f32_16x16x32_bf16(f[b][m], f[b][4 + n], acc[m][n], 0, 0, 0);
            }
    }
#undef LOADSET

    const int ar = lane & 15, kg = lane >> 4;
    #pragma unroll
    for (int n = 0; n < 2; ++n) {
        int col = (nt0 + n) * 16 + ar;
        bool valid = col < 240;
        float bv = valid ? bias[col] : 0.f;
        #pragma unroll
        for (int m = 0; m < 2; ++m) {
            #pragma unroll
            for (int r = 0; r < 4; ++r) {
                int row = (mt0 + m) * 16 + kg * 4 + r;
                float v = valid ? fast_tanh(acc[m][n][r] + bv) : 0.f;
                uint16_t hi = bf16_of(v);
                size_t off = packed_off(row, col, 256);
                Ohi[off] = hi;
                Olo[off] = bf16_of(v - bf16_to_f(hi));
            }
        }
    }
}

// ---------------------------------------------------------------------------
// Fused small GEMM (K=256, A split hi/lo, 3-term) with bias+tanh epilogue,
// writing bf16 hi/lo PACKED directly (middle fitting layer).
// ---------------------------------------------------------------------------
template<int KP>
__global__ __launch_bounds__(256, 4) void gemm_fused(
    const uint16_t* __restrict__ Ahi, const uint16_t* __restrict__ Alo,
    const uint16_t* __restrict__ Wthi, const uint16_t* __restrict__ Wtlo,
    const float* __restrict__ bias,
    uint16_t* __restrict__ Ohi, uint16_t* __restrict__ Olo)
{
    constexpr int KT = KP >> 5;
    const int tid = threadIdx.x;
    const int wid = tid >> 6, lane = tid & 63;
    const int mg = wid >> 1, ng = wid & 1;
    const int mt0 = blockIdx.x * 4 + mg * 2;
    const int nt0 = blockIdx.y * 4 + ng * 2;

    const size_t aB0 = ((size_t)(mt0 + 0) * KT) * 512 + lane * 8;
    const size_t aB1 = ((size_t)(mt0 + 1) * KT) * 512 + lane * 8;
    const size_t bB0 = ((size_t)(nt0 + 0) * KT) * 512 + lane * 8;
    const size_t bB1 = ((size_t)(nt0 + 1) * KT) * 512 + lane * 8;

    f32x4 acc[2][2];
    #pragma unroll
    for (int m = 0; m < 2; ++m)
        #pragma unroll
        for (int n = 0; n < 2; ++n) acc[m][n] = (f32x4){0.f, 0.f, 0.f, 0.f};

    short8v f[2][8];

#define LOADSET(B, S) do {                                       \
        f[B][0] = *(const short8v*)(Ahi  + aB0 + (S) * 512);     \
        f[B][1] = *(const short8v*)(Ahi  + aB1 + (S) * 512);     \
        f[B][2] = *(const short8v*)(Alo  + aB0 + (S) * 512);     \
        f[B][3] = *(const short8v*)(Alo  + aB1 + (S) * 512);     \
        f[B][4] = *(const short8v*)(Wthi + bB0 + (S) * 512);     \
        f[B][5] = *(const short8v*)(Wthi + bB1 + (S) * 512);     \
        f[B][6] = *(const short8v*)(Wtlo + bB0 + (S) * 512);     \
        f[B][7] = *(const short8v*)(Wtlo + bB1 + (S) * 512);     \
    } while (0)

    LOADSET(0, 0);
    #pragma unroll
    for (int s = 0; s < KT; ++s) {
        const int b = s & 1;
        if (s + 1 < KT) LOADSET(b ^ 1, s + 1);
        #pragma unroll
        for (int m = 0; m < 2; ++m)
            #pragma unroll
            for (int n = 0; n < 2; ++n) {
                acc[m][n] = __builtin_amdgcn_mfma_f32_16x16x32_bf16(f[b][m],     f[b][4 + n], acc[m][n], 0, 0, 0);
                acc[m][n] = __builtin_amdgcn_mfma_f32_16x16x32_bf16(f[b][m],     f[b][6 + n], acc[m][n], 0, 0, 0);
                acc[m][n] = __builtin_amdgcn_mfma_f32_16x16x32_bf16(f[b][2 + m], f[b][4 + n], acc[m][n], 0, 0, 0);
            }
    }
#undef LOADSET

    const int ar = lane & 15, kg = lane >> 4;
    #pragma unroll
    for (int n = 0; n < 2; ++n) {
        int col = (nt0 + n) * 16 + ar;
        bool valid = col < 240;
        float bv = valid ? bias[col] : 0.f;
        #pragma unroll
        for (int m = 0; m < 2; ++m) {
            #pragma unroll
            for (int r = 0; r < 4; ++r) {
                int row = (mt0 + m) * 16 + kg * 4 + r;
                float v = valid ? fast_tanh(acc[m][n][r] + bv) : 0.f;
                uint16_t hi = bf16_of(v);
                size_t off = packed_off(row, col, 256);
                Ohi[off] = hi;
                Olo[off] = bf16_of(v - bf16_to_f(hi));
            }
        }
    }
}

// ---------------------------------------------------------------------------
// Last fitting GEMM (K=256, 3-term) + fused Wf3 dot: h3 never materialized.
// Each WAVE owns a disjoint 32-col slice: partial index = by*2 + ng (8 total).
// ---------------------------------------------------------------------------
template<int KP>
__global__ __launch_bounds__(256, 4) void gemm_fused_dot(
    const uint16_t* __restrict__ Ahi, const uint16_t* __restrict__ Alo,
    const uint16_t* __restrict__ Wthi, const uint16_t* __restrict__ Wtlo,
    const float* __restrict__ bias, const float* __restrict__ Wf3,
    float* __restrict__ EiPart)
{
    constexpr int KT = KP >> 5;
    const int tid = threadIdx.x;
    const int wid = tid >> 6, lane = tid & 63;
    const int mg = wid >> 1, ng = wid & 1;
    const int mt0 = blockIdx.x * 4 + mg * 2;
    const int nt0 = blockIdx.y * 4 + ng * 2;

    const size_t aB0 = ((size_t)(mt0 + 0) * KT) * 512 + lane * 8;
    const size_t aB1 = ((size_t)(mt0 + 1) * KT) * 512 + lane * 8;
    const size_t bB0 = ((size_t)(nt0 + 0) * KT) * 512 + lane * 8;
    const size_t bB1 = ((size_t)(nt0 + 1) * KT) * 512 + lane * 8;

    f32x4 acc[2][2];
    #pragma unroll
    for (int m = 0; m < 2; ++m)
        #pragma unroll
        for (int n = 0; n < 2; ++n) acc[m][n] = (f32x4){0.f, 0.f, 0.f, 0.f};

    short8v f[2][8];

#define LOADSET(B, S) do {                                       \
        f[B][0] = *(const short8v*)(Ahi  + aB0 + (S) * 512);     \
        f[B][1] = *(const short8v*)(Ahi  + aB1 + (S) * 512);     \
        f[B][2] = *(const short8v*)(Alo  + aB0 + (S) * 512);     \
        f[B][3] = *(const short8v*)(Alo  + aB1 + (S) * 512);     \
        f[B][4] = *(const short8v*)(Wthi + bB0 + (S) * 512);     \
        f[B][5] = *(const short8v*)(Wthi + bB1 + (S) * 512);     \
        f[B][6] = *(const short8v*)(Wtlo + bB0 + (S) * 512);     \
        f[B][7] = *(const short8v*)(Wtlo + bB1 + (S) * 512);     \
    } while (0)

    LOADSET(0, 0);
    #pragma unroll
    for (int s = 0; s < KT; ++s) {
        const int b = s & 1;
        if (s + 1 < KT) LOADSET(b ^ 1, s + 1);
        #pragma unroll
        for (int m = 0; m < 2; ++m)
            #pragma unroll
            for (int n = 0; n < 2; ++n) {
                acc[m][n] = __builtin_amdgcn_mfma_f32_16x16x32_bf16(f[b][m],     f[b][4 + n], acc[m][n], 0, 0, 0);
                acc[m][n] = __builtin_amdgcn_mfma_f32_16x16x32_bf16(f[b][m],     f[b][6 + n], acc[m][n], 0, 0, 0);
                acc[m][n] = __builtin_amdgcn_mfma_f32_16x16x32_bf16(f[b][2 + m], f[b][4 + n], acc[m][n], 0, 0, 0);
            }
    }
#undef LOADSET

    const int ar = lane & 15, kg = lane >> 4;
    float p[2][4];
    #pragma unroll
    for (int m = 0; m < 2; ++m)
        #pragma unroll
        for (int r = 0; r < 4; ++r) p[m][r] = 0.f;

    #pragma unroll
    for (int n = 0; n < 2; ++n) {
        int col = (nt0 + n) * 16 + ar;
        bool valid = col < 240;
        float bv = valid ? bias[col] : 0.f;
        float w3 = valid ? Wf3[col] : 0.f;
        #pragma unroll
        for (int m = 0; m < 2; ++m) {
            #pragma unroll
            for (int r = 0; r < 4; ++r) {
                float v = valid ? fast_tanh(acc[m][n][r] + bv) : 0.f;
                p[m][r] = fmaf(v, w3, p[m][r]);
            }
        }
    }
    #pragma unroll
    for (int m = 0; m < 2; ++m)
        #pragma unroll
        for (int r = 0; r < 4; ++r) {
            p[m][r] += __shfl_xor(p[m][r], 1, 64);
            p[m][r] += __shfl_xor(p[m][r], 2, 64);
            p[m][r] += __shfl_xor(p[m][r], 4, 64);
            p[m][r] += __shfl_xor(p[m][r], 8, 64);
        }
    if (ar == 0) {
        const int slice = blockIdx.y * 2 + ng;   // 8 disjoint col-slices
        #pragma unroll
        for (int m = 0; m < 2; ++m)
            #pragma unroll
            for (int r = 0; r < 4; ++r) {
                int row = (mt0 + m) * 16 + kg * 4 + r;
                EiPart[(size_t)slice * 8192 + row] = p[m][r];
            }
    }
}

// ---------------------------------------------------------------------------
// Ei = sum over 8 slices of EiPart + bf3; Etot[b] = sum Ei. One block per b.
// ---------------------------------------------------------------------------
__global__ __launch_bounds__(256) void ei_etot_kernel(
    const float* __restrict__ EiPart, const float* __restrict__ bf3,
    float* __restrict__ out)
{
    __shared__ float red[256];
    int b = blockIdx.x, t = threadIdx.x;
    float b3 = bf3[0];
    float s = 0.f;
    for (int i = t; i < NN; i += 256) {
        int atom = b * NN + i;
        float e = b3;
        #pragma unroll
        for (int z = 0; z < 8; ++z) e += EiPart[(size_t)z * 8192 + atom];
        out[4 + atom] = e;
        s += e;
    }
    red[t] = s;
    __syncthreads();
    for (int w = 128; w; w >>= 1) {
        if (t < w) red[t] += red[t + w];
        __syncthreads();
    }
    if (t == 0) out[b] = red[0];
}

// ---------------------------------------------------------------------------
extern "C" void kernel_launch(void* const* d_in, const int* in_sizes, int n_in,
                              void* d_out, int out_size, void* d_ws, size_t ws_size,
                              hipStream_t stream)
{
    const float* dR    = (const float*)d_in[0];
    const int*   neigh = (const int*)d_in[1];
    const float* We0   = (const float*)d_in[2];
    const float* be0   = (const float*)d_in[3];
    const float* We1   = (const float*)d_in[4];
    const float* be1   = (const float*)d_in[5];
    const float* We2   = (const float*)d_in[6];
    const float* be2   = (const float*)d_in[7];
    const float* Wf0   = (const float*)d_in[8];
    const float* bf0   = (const float*)d_in[9];
    const float* Wf1   = (const float*)d_in[10];
    const float* bf1   = (const float*)d_in[11];
    const float* Wf2   = (const float*)d_in[12];
    const float* bf2   = (const float*)d_in[13];
    const float* Wf3   = (const float*)d_in[14];
    const float* bf3   = (const float*)d_in[15];
    float* out = (float*)d_out;

    char* ws = (char*)d_ws;
    uint16_t* Wt0hi  = (uint16_t*)(ws + 32768);               // 819200
    uint16_t* Wt0lo  = (uint16_t*)(ws + 851968);              // 819200
    uint16_t* Wt1hi  = (uint16_t*)(ws + 1671168);             // 131072
    uint16_t* Wt1lo  = (uint16_t*)(ws + 1802240);             // 131072
    uint16_t* Wt2hi  = (uint16_t*)(ws + 1933312);             // 131072
    uint16_t* Wt2lo  = (uint16_t*)(ws + 2064384);             // 131072
    uint16_t* DRhi   = (uint16_t*)(ws + 2195456);             // 26214400
    uint16_t* hAhi   = (uint16_t*)(ws + 54624256);            // 4194304
    uint16_t* hAlo   = (uint16_t*)(ws + 58818560);            // 4194304
    uint16_t* hBhi   = (uint16_t*)(ws + 63012864);            // 4194304
    uint16_t* hBlo   = (uint16_t*)(ws + 67207168);            // 4194304
    float*    EiPart = (float*)(ws + 71401472);               // 262144 (8 slices)
    // TBLP bf16-pair table (819200) aliases hBhi: written by prep_table_fused,
    // read only by desc, dead before gemm_fused writes hB.
    uint32_t* TBLP = (uint32_t*)(ws + 63012864);

    prep_table_fused<<<256, 256, 0, stream>>>(We0, be0, We1, be1, We2, be2, TBLP);
    prep_wt_all_kernel<<<2112, 256, 0, stream>>>(Wf0, Wf1, Wf2,
                                                 Wt0hi, Wt0lo, Wt1hi, Wt1lo,
                                                 Wt2hi, Wt2lo);

    desc_kernel<<<NB * NN, 256, 0, stream>>>(dR, neigh, TBLP, DRhi);

    gemm1_fused<1600><<<dim3(128, 4), 256, 0, stream>>>(DRhi, Wt0hi, Wt0lo, bf0, hAhi, hAlo);
    gemm_fused<256><<<dim3(128, 4), 256, 0, stream>>>(hAhi, hAlo, Wt1hi, Wt1lo, bf1, hBhi, hBlo);
    gemm_fused_dot<256><<<dim3(128, 4), 256, 0, stream>>>(hBhi, hBlo, Wt2hi, Wt2lo, bf2, Wf3, EiPart);

    ei_etot_kernel<<<NB, 256, 0, stream>>>(EiPart, bf3, out);
}